// Round 1
// baseline (1229.267 us; speedup 1.0000x reference)
//
#include <hip/hip_runtime.h>
#include <math.h>

#define IN_DIM   128
#define EDGE_DIM 64
#define ED       64   // EMBED_DIM
#define NH       8    // heads
// head_dim = 8

// ---- order-preserving float <-> uint encoding for atomicMax ----
__device__ __forceinline__ unsigned fkey(float f) {
    unsigned u = __float_as_uint(f);
    return (u & 0x80000000u) ? ~u : (u | 0x80000000u);
}
__device__ __forceinline__ float funkey(unsigned k) {
    return (k & 0x80000000u) ? __uint_as_float(k ^ 0x80000000u)
                             : __uint_as_float(~k);
}

// ---- K1: nodes = node_features @ W + b  ([nN,128] x [128,64]) ----
__global__ void node_proj(const float* __restrict__ nf,
                          const float* __restrict__ W,
                          const float* __restrict__ Wb,
                          float* __restrict__ nodes, int nN) {
    __shared__ float W_s[IN_DIM * ED];      // 32 KB
    __shared__ float nf_s[4][IN_DIM];       // 2 KB
    int t = threadIdx.x;
    for (int i = t; i < IN_DIM * ED; i += 256) W_s[i] = W[i];
    int sub = t >> 6, j = t & 63;
    long n = (long)blockIdx.x * 4 + sub;
    if (n < nN) {
        nf_s[sub][j]      = nf[n * IN_DIM + j];
        nf_s[sub][j + 64] = nf[n * IN_DIM + j + 64];
    }
    __syncthreads();
    if (n >= nN) return;
    float acc = Wb[j];
#pragma unroll
    for (int k = 0; k < IN_DIM; k++) acc += nf_s[sub][k] * W_s[k * ED + j];
    nodes[n * ED + j] = acc;
}

// ---- K2: per-edge logits + segment max ----
__global__ void edge_pass1(const float* __restrict__ ef,
                           const int* __restrict__ snd,
                           const int* __restrict__ rcv,
                           const float* __restrict__ nodes,
                           const float* __restrict__ We,
                           const float* __restrict__ Web,
                           const float* __restrict__ a,
                           float* __restrict__ logits,
                           unsigned* __restrict__ maxu, int nE) {
    __shared__ float We_s[EDGE_DIM * ED];   // 16 KB
    __shared__ float a_s[ED];
    __shared__ float ef_s[4][EDGE_DIM];
    int t = threadIdx.x;
    for (int i = t; i < EDGE_DIM * ED; i += 256) We_s[i] = We[i];
    if (t < ED) a_s[t] = a[t];
    int sub = t >> 6, j = t & 63;
    long e = (long)blockIdx.x * 4 + sub;
    bool valid = (e < nE);
    ef_s[sub][j] = valid ? ef[e * EDGE_DIM + j] : 0.f;
    __syncthreads();
    if (!valid) return;
    int s = snd[e], r = rcv[e];
    float acc = Web[j];
#pragma unroll
    for (int k = 0; k < EDGE_DIM; k++) acc += ef_s[sub][k] * We_s[k * ED + j];
    float x = nodes[(long)s * ED + j] + nodes[(long)r * ED + j] + acc;
    // mish(x) = x * tanh(softplus(x)), numerically stable softplus
    float sp = (x > 0.f) ? (x + log1pf(__expf(-x))) : log1pf(__expf(x));
    float m  = x * tanhf(sp);
    float p  = m * a_s[j];
    // reduce over head_dim=8 (lanes j, j^1, j^2, j^4 within 8-lane group)
    p += __shfl_xor(p, 1);
    p += __shfl_xor(p, 2);
    p += __shfl_xor(p, 4);
    if ((j & 7) == 0) {
        int h = j >> 3;
        logits[e * NH + h] = p;
        atomicMax(&maxu[(long)r * NH + h], fkey(p));
    }
}

// ---- K3: w = exp(l - mx); accumulate numerator & denominator ----
__global__ void edge_pass2(const int* __restrict__ snd,
                           const int* __restrict__ rcv,
                           const float* __restrict__ nodes,
                           const float* __restrict__ logits,
                           const unsigned* __restrict__ maxu,
                           float* __restrict__ out,
                           float* __restrict__ den, int nE) {
    long t = (long)blockIdx.x * 256 + threadIdx.x;
    long e = t >> 6;
    if (e >= nE) return;
    int j = (int)(t & 63);
    int s = snd[e], r = rcv[e];
    int h = j >> 3;
    float l  = logits[e * NH + h];
    float mx = funkey(maxu[(long)r * NH + h]);
    float w  = __expf(l - mx);
    float sv = nodes[(long)s * ED + j];
    atomicAdd(&out[(long)r * ED + j], w * sv);
    if ((j & 7) == 0) atomicAdd(&den[(long)r * NH + h], w);
}

// ---- K4: normalize ----
__global__ void node_div(float* __restrict__ out,
                         const float* __restrict__ den, int nN) {
    long t = (long)blockIdx.x * 256 + threadIdx.x;
    if (t >= (long)nN * ED) return;
    int n = (int)(t >> 6), j = (int)(t & 63), h = j >> 3;
    float d = den[(long)n * NH + h];
    out[t] = (d > 0.f) ? out[t] / d : 0.f;
}

extern "C" void kernel_launch(void* const* d_in, const int* in_sizes, int n_in,
                              void* d_out, int out_size, void* d_ws, size_t ws_size,
                              hipStream_t stream) {
    const float* nf  = (const float*)d_in[0];
    const float* ef  = (const float*)d_in[1];
    // d_in[2] = global_features (unused by reference output)
    const int*   snd = (const int*)d_in[3];
    const int*   rcv = (const int*)d_in[4];
    const float* W   = (const float*)d_in[5];
    const float* Wb  = (const float*)d_in[6];
    const float* We  = (const float*)d_in[7];
    const float* Web = (const float*)d_in[8];
    const float* a   = (const float*)d_in[9];

    int nN = in_sizes[0] / IN_DIM;
    int nE = in_sizes[3];
    float* out = (float*)d_out;

    float*    nodes  = (float*)d_ws;                         // nN*64
    float*    logits = nodes + (size_t)nN * ED;              // nE*8
    unsigned* maxu   = (unsigned*)(logits + (size_t)nE * NH); // nN*8
    float*    den    = (float*)(maxu + (size_t)nN * NH);     // nN*8

    hipMemsetAsync(out,  0, (size_t)nN * ED * sizeof(float), stream);
    hipMemsetAsync(maxu, 0, (size_t)nN * NH * sizeof(unsigned), stream);
    hipMemsetAsync(den,  0, (size_t)nN * NH * sizeof(float), stream);

    node_proj<<<(nN + 3) / 4, 256, 0, stream>>>(nf, W, Wb, nodes, nN);
    edge_pass1<<<(nE + 3) / 4, 256, 0, stream>>>(ef, snd, rcv, nodes, We, Web, a,
                                                 logits, maxu, nE);
    long th2 = (long)nE * 64;
    edge_pass2<<<(int)((th2 + 255) / 256), 256, 0, stream>>>(snd, rcv, nodes, logits,
                                                             maxu, out, den, nE);
    long th4 = (long)nN * ED;
    node_div<<<(int)((th4 + 255) / 256), 256, 0, stream>>>(out, den, nN);
}

// Round 2
// 582.358 us; speedup vs baseline: 2.1108x; 2.1108x over previous
//
#include <hip/hip_runtime.h>
#include <math.h>

#define IN_DIM   128
#define EDGE_DIM 64
#define ED       64   // EMBED_DIM
#define NH       8    // heads

typedef __attribute__((ext_vector_type(8))) __bf16 bf16x8;
typedef __attribute__((ext_vector_type(4))) float  f32x4;

// ---- order-preserving float <-> uint encoding for atomicMax ----
__device__ __forceinline__ unsigned fkey(float f) {
    unsigned u = __float_as_uint(f);
    return (u & 0x80000000u) ? ~u : (u | 0x80000000u);
}
__device__ __forceinline__ float funkey(unsigned k) {
    return (k & 0x80000000u) ? __uint_as_float(k ^ 0x80000000u)
                             : __uint_as_float(~k);
}

// exact mish: x * (u^2+2u)/(u^2+2u+2), u = e^x (clamped; exact to fp32 for x>15)
__device__ __forceinline__ float mish_f(float x) {
    float u  = __expf(fminf(x, 15.f));
    float nn = u * (u + 2.f);
    return x * __fdividef(nn, nn + 2.f);
}

// ---- K1: nodes = nf @ W + b  via MFMA. One wave = 16 nodes. ----
__global__ void node_proj(const float* __restrict__ nf,
                          const float* __restrict__ W,
                          const float* __restrict__ Wb,
                          float* __restrict__ nodes, int nN) {
    int lane = threadIdx.x & 63;
    int col  = lane & 15;         // node-within-group (B n-index, C col)
    int q    = lane >> 4;
    int wid    = blockIdx.x * (blockDim.x >> 6) + (threadIdx.x >> 6);
    int nwaves = gridDim.x * (blockDim.x >> 6);

    // A = W^T fragments: A[m=j', k] = W[k*64 + j'], j' = c*16+col, k = s*32+q*8+i
    bf16x8 aw[4][4];
#pragma unroll
    for (int c = 0; c < 4; c++)
#pragma unroll
        for (int s = 0; s < 4; s++)
#pragma unroll
            for (int i = 0; i < 8; i++)
                aw[c][s][i] = (__bf16)W[(s * 32 + q * 8 + i) * ED + c * 16 + col];
    f32x4 wbv[4];
#pragma unroll
    for (int c = 0; c < 4; c++)
#pragma unroll
        for (int r = 0; r < 4; r++)
            wbv[c][r] = Wb[c * 16 + q * 4 + r];

    int ngroups = (nN + 15) >> 4;
    for (int g = wid; g < ngroups; g += nwaves) {
        int n = g * 16 + col;
        bool valid = (n < nN);
        long nb = (long)(valid ? n : nN - 1) * IN_DIM;
        bf16x8 bfr[4];
#pragma unroll
        for (int s = 0; s < 4; s++) {
            float4 f0 = *(const float4*)(nf + nb + s * 32 + q * 8);
            float4 f1 = *(const float4*)(nf + nb + s * 32 + q * 8 + 4);
            bfr[s][0] = (__bf16)f0.x; bfr[s][1] = (__bf16)f0.y;
            bfr[s][2] = (__bf16)f0.z; bfr[s][3] = (__bf16)f0.w;
            bfr[s][4] = (__bf16)f1.x; bfr[s][5] = (__bf16)f1.y;
            bfr[s][6] = (__bf16)f1.z; bfr[s][7] = (__bf16)f1.w;
        }
        f32x4 acc[4];
#pragma unroll
        for (int c = 0; c < 4; c++) {
            acc[c] = wbv[c];
#pragma unroll
            for (int s = 0; s < 4; s++)
                acc[c] = __builtin_amdgcn_mfma_f32_16x16x32_bf16(aw[c][s], bfr[s], acc[c], 0, 0, 0);
        }
        if (valid) {
#pragma unroll
            for (int c = 0; c < 4; c++) {
                int j0 = c * 16 + q * 4;
                float4 v = make_float4(acc[c][0], acc[c][1], acc[c][2], acc[c][3]);
                *(float4*)(nodes + (long)n * ED + j0) = v;
            }
        }
    }
}

// ---- K2: fused edge GEMM + mish + logits + segment max. One wave = 16 edges. ----
__global__ void edge_pass1(const float* __restrict__ ef,
                           const int* __restrict__ snd,
                           const int* __restrict__ rcv,
                           const float* __restrict__ nodes,
                           const float* __restrict__ We,
                           const float* __restrict__ Web,
                           const float* __restrict__ a,
                           float* __restrict__ logits,
                           unsigned* __restrict__ maxu, int nE) {
    int lane = threadIdx.x & 63;
    int col  = lane & 15;         // edge-within-group
    int q    = lane >> 4;
    int wid    = blockIdx.x * (blockDim.x >> 6) + (threadIdx.x >> 6);
    int nwaves = gridDim.x * (blockDim.x >> 6);

    // A = We^T fragments: A[m=j', k] = We[k*64 + j']
    bf16x8 aw[4][2];
#pragma unroll
    for (int c = 0; c < 4; c++)
#pragma unroll
        for (int s = 0; s < 2; s++)
#pragma unroll
            for (int i = 0; i < 8; i++)
                aw[c][s][i] = (__bf16)We[(s * 32 + q * 8 + i) * ED + c * 16 + col];
    f32x4 wbv[4];
    float ahat[4][4];
#pragma unroll
    for (int c = 0; c < 4; c++)
#pragma unroll
        for (int r = 0; r < 4; r++) {
            int j = c * 16 + q * 4 + r;
            wbv[c][r]  = Web[j];
            ahat[c][r] = a[j];
        }

    int ngroups = (nE + 15) >> 4;
    for (int g = wid; g < ngroups; g += nwaves) {
        int e = g * 16 + col;
        bool valid = (e < nE);
        long eb = (long)(valid ? e : nE - 1) * EDGE_DIM;
        bf16x8 bfr[2];
#pragma unroll
        for (int s = 0; s < 2; s++) {
            float4 f0 = *(const float4*)(ef + eb + s * 32 + q * 8);
            float4 f1 = *(const float4*)(ef + eb + s * 32 + q * 8 + 4);
            bfr[s][0] = (__bf16)f0.x; bfr[s][1] = (__bf16)f0.y;
            bfr[s][2] = (__bf16)f0.z; bfr[s][3] = (__bf16)f0.w;
            bfr[s][4] = (__bf16)f1.x; bfr[s][5] = (__bf16)f1.y;
            bfr[s][6] = (__bf16)f1.z; bfr[s][7] = (__bf16)f1.w;
        }
        f32x4 acc[4];
#pragma unroll
        for (int c = 0; c < 4; c++) {
            acc[c] = wbv[c];
            acc[c] = __builtin_amdgcn_mfma_f32_16x16x32_bf16(aw[c][0], bfr[0], acc[c], 0, 0, 0);
            acc[c] = __builtin_amdgcn_mfma_f32_16x16x32_bf16(aw[c][1], bfr[1], acc[c], 0, 0, 0);
        }
        int ec = valid ? e : nE - 1;
        int se = snd[ec], re = rcv[ec];
        float p[4];
#pragma unroll
        for (int c = 0; c < 4; c++) {
            int j0 = c * 16 + q * 4;
            float4 sv = *(const float4*)(nodes + (long)se * ED + j0);
            float4 rv = *(const float4*)(nodes + (long)re * ED + j0);
            float xs[4] = {sv.x + rv.x, sv.y + rv.y, sv.z + rv.z, sv.w + rv.w};
            float ph = 0.f;
#pragma unroll
            for (int r = 0; r < 4; r++) {
                float x = acc[c][r] + xs[r];
                ph = fmaf(mish_f(x), ahat[c][r], ph);
            }
            p[c] = ph;
        }
        // head h = c*2 + (q>>1); partner quad is lane^16
#pragma unroll
        for (int c = 0; c < 4; c++) p[c] += __shfl_xor(p[c], 16);
        if (valid && ((q & 1) == 0)) {
            int hb = q >> 1;   // 0 -> even heads, 1 -> odd heads
#pragma unroll
            for (int c = 0; c < 4; c++) {
                int h = c * 2 + hb;
                float v = p[c];
                logits[(long)e * NH + h] = v;
                atomicMax(&maxu[(long)re * NH + h], fkey(v));
            }
        }
    }
}

// ---- K3: w = exp(l - mx); accumulate numerator & denominator ----
__global__ void edge_pass2(const int* __restrict__ snd,
                           const int* __restrict__ rcv,
                           const float* __restrict__ nodes,
                           const float* __restrict__ logits,
                           const unsigned* __restrict__ maxu,
                           float* __restrict__ out,
                           float* __restrict__ den, int nE) {
    long t = (long)blockIdx.x * 256 + threadIdx.x;
    long e = t >> 6;
    if (e >= nE) return;
    int j = (int)(t & 63);
    int s = snd[e], r = rcv[e];
    int h = j >> 3;
    float l  = logits[e * NH + h];
    float mx = funkey(maxu[(long)r * NH + h]);
    float w  = __expf(l - mx);
    float sv = nodes[(long)s * ED + j];
    atomicAdd(&out[(long)r * ED + j], w * sv);
    if ((j & 7) == 0) atomicAdd(&den[(long)r * NH + h], w);
}

// ---- K4: normalize ----
__global__ void node_div(float* __restrict__ out,
                         const float* __restrict__ den, int nN) {
    long t = (long)blockIdx.x * 256 + threadIdx.x;
    if (t >= (long)nN * ED) return;
    int n = (int)(t >> 6), j = (int)(t & 63), h = j >> 3;
    float d = den[(long)n * NH + h];
    out[t] = (d > 0.f) ? out[t] / d : 0.f;
}

extern "C" void kernel_launch(void* const* d_in, const int* in_sizes, int n_in,
                              void* d_out, int out_size, void* d_ws, size_t ws_size,
                              hipStream_t stream) {
    const float* nf  = (const float*)d_in[0];
    const float* ef  = (const float*)d_in[1];
    const int*   snd = (const int*)d_in[3];
    const int*   rcv = (const int*)d_in[4];
    const float* W   = (const float*)d_in[5];
    const float* Wb  = (const float*)d_in[6];
    const float* We  = (const float*)d_in[7];
    const float* Web = (const float*)d_in[8];
    const float* a   = (const float*)d_in[9];

    int nN = in_sizes[0] / IN_DIM;
    int nE = in_sizes[3];
    float* out = (float*)d_out;

    float*    nodes  = (float*)d_ws;                          // nN*64
    float*    logits = nodes + (size_t)nN * ED;               // nE*8
    unsigned* maxu   = (unsigned*)(logits + (size_t)nE * NH); // nN*8
    float*    den    = (float*)(maxu + (size_t)nN * NH);      // nN*8

    hipMemsetAsync(out,  0, (size_t)nN * ED * sizeof(float), stream);
    hipMemsetAsync(maxu, 0, (size_t)nN * NH * sizeof(unsigned), stream);
    hipMemsetAsync(den,  0, (size_t)nN * NH * sizeof(float), stream);

    node_proj<<<256, 256, 0, stream>>>(nf, W, Wb, nodes, nN);
    edge_pass1<<<1024, 256, 0, stream>>>(ef, snd, rcv, nodes, We, Web, a,
                                         logits, maxu, nE);
    long th2 = (long)nE * 64;
    edge_pass2<<<(int)((th2 + 255) / 256), 256, 0, stream>>>(snd, rcv, nodes, logits,
                                                             maxu, out, den, nE);
    long th4 = (long)nN * ED;
    node_div<<<(int)((th4 + 255) / 256), 256, 0, stream>>>(out, den, nN);
}